// Round 1
// baseline (1487.646 us; speedup 1.0000x reference)
//
#include <hip/hip_runtime.h>

#define F 128  // feature dim, fixed by the problem

// ---------------------------------------------------------------------------
// Kernel 1: edge scatter-add.  One 64-lane wave per edge: lane l handles
// feature elements [2l, 2l+1] (float2).  Gather feature[src] (L2/L3-resident,
// 25.6 MB) and atomically accumulate into h[dst].
// unsafeAtomicAdd -> global_atomic_add_f32 (HW fp32 atomic, no CAS loop).
// ---------------------------------------------------------------------------
__global__ __launch_bounds__(256) void gcn_scatter(
    const float2* __restrict__ feat,   // [N][64] as float2
    const int* __restrict__ src,
    const int* __restrict__ dst,
    float* __restrict__ h,             // [N][128] accumulator (pre-zeroed)
    int E) {
  const int lane  = threadIdx.x & 63;
  const int wave  = blockIdx.x * (blockDim.x >> 6) + (threadIdx.x >> 6);
  const int nwave = gridDim.x * (blockDim.x >> 6);
  for (int e = wave; e < E; e += nwave) {
    const int s = src[e];              // wave-uniform (single L1 request)
    const int d = dst[e];
    const float2 v = feat[(size_t)s * 64 + lane];
    float* hp = h + (size_t)d * F + lane * 2;
    unsafeAtomicAdd(hp,     v.x);
    unsafeAtomicAdd(hp + 1, v.y);
  }
}

// ---------------------------------------------------------------------------
// Kernel 2: out = h @ W^T + b   (fp32 vector GEMM — no fp32 MFMA on CDNA4).
// W^T staged in LDS once per block (Wt[k][j] = W[j][k] so the inner read
// Wt[k*128+j] is conflict-free: consecutive j -> consecutive banks).
// Block = 256 threads; 8 rows per iteration; each thread computes 4 outputs
// (4 rows x 1 col) so the Wt read is amortized 4x.
// ---------------------------------------------------------------------------
__global__ __launch_bounds__(256) void gcn_gemm(
    const float* __restrict__ h,
    const float* __restrict__ W,       // [128][128] row-major, out = h @ W^T
    const float* __restrict__ b,
    float* __restrict__ out,
    int N) {
  __shared__ float Wt[F * F];          // 64 KiB
  __shared__ float hrow[8][F];         // 4 KiB

  // Cooperative transposed load of W (once per block; write conflicts are
  // a one-time cost).
  for (int idx = threadIdx.x; idx < F * F; idx += 256) {
    const int j = idx >> 7, k = idx & 127;
    Wt[k * F + j] = W[idx];
  }
  const int j    = threadIdx.x & 127;  // output column
  const int half = threadIdx.x >> 7;   // 0/1 -> rows [0..3] or [4..7]
  const float bj = b[j];
  __syncthreads();

  for (int i0 = blockIdx.x * 8; i0 < N; i0 += gridDim.x * 8) {
    // Stage 8 rows of h into LDS (coalesced: linear tid over 1024 elems).
    #pragma unroll
    for (int p = 0; p < 4; ++p) {
      const int idx = threadIdx.x + p * 256;   // 0..1023
      const int r = idx >> 7, c = idx & 127;
      const int i = i0 + r;
      hrow[r][c] = (i < N) ? h[(size_t)i * F + c] : 0.f;
    }
    __syncthreads();

    float acc0 = bj, acc1 = bj, acc2 = bj, acc3 = bj;
    const int rbase = half * 4;
    #pragma unroll
    for (int k = 0; k < F; ++k) {
      const float w = Wt[k * F + j];           // conflict-free across lanes
      acc0 += hrow[rbase + 0][k] * w;          // broadcast reads
      acc1 += hrow[rbase + 1][k] * w;
      acc2 += hrow[rbase + 2][k] * w;
      acc3 += hrow[rbase + 3][k] * w;
    }
    const int i = i0 + rbase;
    if (i + 0 < N) out[(size_t)(i + 0) * F + j] = acc0;
    if (i + 1 < N) out[(size_t)(i + 1) * F + j] = acc1;
    if (i + 2 < N) out[(size_t)(i + 2) * F + j] = acc2;
    if (i + 3 < N) out[(size_t)(i + 3) * F + j] = acc3;
    __syncthreads();
  }
}

extern "C" void kernel_launch(void* const* d_in, const int* in_sizes, int n_in,
                              void* d_out, int out_size, void* d_ws, size_t ws_size,
                              hipStream_t stream) {
  const float* feat = (const float*)d_in[0];
  const int*   src  = (const int*)d_in[1];
  const int*   dst  = (const int*)d_in[2];
  const float* W    = (const float*)d_in[3];
  const float* b    = (const float*)d_in[4];
  float*       out  = (float*)d_out;

  const int N = in_sizes[0] / F;   // 50000
  const int E = in_sizes[1];       // 1600000

  float* h = (float*)d_ws;         // [N][128] fp32 accumulator, 25.6 MB

  // Zero the accumulator every call (graph-capture-safe memset node).
  hipMemsetAsync(h, 0, (size_t)N * F * sizeof(float), stream);

  // 2048 blocks x 4 waves = 8192 waves; ~195 edges each (full occupancy).
  gcn_scatter<<<2048, 256, 0, stream>>>((const float2*)feat, src, dst, h, E);

  // 1024 blocks; 8 rows / block-iteration.
  gcn_gemm<<<1024, 256, 0, stream>>>(h, W, b, out, N);
}

// Round 2
// 580.661 us; speedup vs baseline: 2.5620x; 2.5620x over previous
//
#include <hip/hip_runtime.h>

#define F 128  // feature dim, fixed by the problem

// ---------------------------------------------------------------------------
// CSR build, step 1: histogram of dst.  1.6M int atomics on 50K counters —
// ~1.6% of the old fp32 atomic count.
// ---------------------------------------------------------------------------
__global__ __launch_bounds__(256) void k_hist(
    const int* __restrict__ dst, int* __restrict__ counts, int E) {
  const int stride = gridDim.x * blockDim.x;
  for (int e = blockIdx.x * blockDim.x + threadIdx.x; e < E; e += stride)
    atomicAdd(&counts[dst[e]], 1);
}

// ---------------------------------------------------------------------------
// CSR build, step 2: exclusive prefix sum over counts[N] -> offsets[N].
// Single block of 1024 threads; each thread serially scans a ~49-element
// chunk, Hillis-Steele scan over the 1024 partials in LDS.
// ---------------------------------------------------------------------------
__global__ __launch_bounds__(1024) void k_scan(
    const int* __restrict__ counts, int* __restrict__ offsets, int N) {
  __shared__ int part[1024];
  const int t = threadIdx.x;
  const int chunk = (N + 1023) >> 10;
  const int lo = t * chunk;
  const int hi = min(lo + chunk, N);
  int s = 0;
  for (int i = lo; i < hi; ++i) s += counts[i];
  part[t] = s;
  __syncthreads();
  for (int d = 1; d < 1024; d <<= 1) {
    const int add = (t >= d) ? part[t - d] : 0;
    __syncthreads();
    part[t] += add;
    __syncthreads();
  }
  int run = (t > 0) ? part[t - 1] : 0;  // exclusive base for this chunk
  for (int i = lo; i < hi; ++i) { offsets[i] = run; run += counts[i]; }
}

// ---------------------------------------------------------------------------
// CSR build, step 3: bin src ids by dst.  cursor starts as a copy of offsets.
// Placement order within a bin is nondeterministic (atomic), which only
// permutes fp32 summation order in the reduce — within tolerance.
// ---------------------------------------------------------------------------
__global__ __launch_bounds__(256) void k_scatter(
    const int* __restrict__ src, const int* __restrict__ dst,
    int* __restrict__ cursor, int* __restrict__ srclist, int E) {
  const int stride = gridDim.x * blockDim.x;
  for (int e = blockIdx.x * blockDim.x + threadIdx.x; e < E; e += stride) {
    const int p = atomicAdd(&cursor[dst[e]], 1);
    srclist[p] = src[e];
  }
}

// ---------------------------------------------------------------------------
// Gather-reduce: one wave per node.  Lane l owns feature elements [2l,2l+1]
// (float2).  Sum incoming feature[src] rows in registers, plain store to h.
// 2x unrolled so two independent 512B row loads are in flight.
// ---------------------------------------------------------------------------
__global__ __launch_bounds__(256) void k_reduce(
    const float2* __restrict__ feat,     // [N][64] as float2
    const int* __restrict__ offsets,
    const int* __restrict__ counts,
    const int* __restrict__ srclist,
    float2* __restrict__ h,              // [N][64] as float2
    int N) {
  const int lane = threadIdx.x & 63;
  const int v    = blockIdx.x * 4 + (threadIdx.x >> 6);
  if (v >= N) return;
  const int off = offsets[v];
  const int deg = counts[v];
  float2 acc = make_float2(0.f, 0.f);
  int k = 0;
  for (; k + 1 < deg; k += 2) {
    const int s0 = srclist[off + k];
    const int s1 = srclist[off + k + 1];
    const float2 v0 = feat[(size_t)s0 * 64 + lane];
    const float2 v1 = feat[(size_t)s1 * 64 + lane];
    acc.x += v0.x + v1.x;
    acc.y += v0.y + v1.y;
  }
  if (k < deg) {
    const int s0 = srclist[off + k];
    const float2 v0 = feat[(size_t)s0 * 64 + lane];
    acc.x += v0.x;
    acc.y += v0.y;
  }
  h[(size_t)v * 64 + lane] = acc;
}

// ---------------------------------------------------------------------------
// out = h @ W^T + b  (fp32 vector GEMM — no fp32 MFMA on CDNA4).  Unchanged
// from R1 (passed, ~150us); revisit if it becomes the top dispatch.
// ---------------------------------------------------------------------------
__global__ __launch_bounds__(256) void gcn_gemm(
    const float* __restrict__ h,
    const float* __restrict__ W,       // [128][128] row-major
    const float* __restrict__ b,
    float* __restrict__ out,
    int N) {
  __shared__ float Wt[F * F];          // 64 KiB
  __shared__ float hrow[8][F];         // 4 KiB

  for (int idx = threadIdx.x; idx < F * F; idx += 256) {
    const int j = idx >> 7, k = idx & 127;
    Wt[k * F + j] = W[idx];
  }
  const int j    = threadIdx.x & 127;  // output column
  const int half = threadIdx.x >> 7;   // rows [0..3] or [4..7]
  const float bj = b[j];
  __syncthreads();

  for (int i0 = blockIdx.x * 8; i0 < N; i0 += gridDim.x * 8) {
    #pragma unroll
    for (int p = 0; p < 4; ++p) {
      const int idx = threadIdx.x + p * 256;
      const int r = idx >> 7, c = idx & 127;
      const int i = i0 + r;
      hrow[r][c] = (i < N) ? h[(size_t)i * F + c] : 0.f;
    }
    __syncthreads();

    float acc0 = bj, acc1 = bj, acc2 = bj, acc3 = bj;
    const int rbase = half * 4;
    #pragma unroll
    for (int k = 0; k < F; ++k) {
      const float w = Wt[k * F + j];
      acc0 += hrow[rbase + 0][k] * w;
      acc1 += hrow[rbase + 1][k] * w;
      acc2 += hrow[rbase + 2][k] * w;
      acc3 += hrow[rbase + 3][k] * w;
    }
    const int i = i0 + rbase;
    if (i + 0 < N) out[(size_t)(i + 0) * F + j] = acc0;
    if (i + 1 < N) out[(size_t)(i + 1) * F + j] = acc1;
    if (i + 2 < N) out[(size_t)(i + 2) * F + j] = acc2;
    if (i + 3 < N) out[(size_t)(i + 3) * F + j] = acc3;
    __syncthreads();
  }
}

extern "C" void kernel_launch(void* const* d_in, const int* in_sizes, int n_in,
                              void* d_out, int out_size, void* d_ws, size_t ws_size,
                              hipStream_t stream) {
  const float* feat = (const float*)d_in[0];
  const int*   src  = (const int*)d_in[1];
  const int*   dst  = (const int*)d_in[2];
  const float* W    = (const float*)d_in[3];
  const float* b    = (const float*)d_in[4];
  float*       out  = (float*)d_out;

  const int N = in_sizes[0] / F;   // 50000
  const int E = in_sizes[1];       // 1600000

  // Workspace layout (~32.6 MB total):
  //   h[N*F] fp32 | counts[N] | offsets[N] | cursor[N] | srclist[E]
  float* h       = (float*)d_ws;
  int*   counts  = (int*)(h + (size_t)N * F);
  int*   offsets = counts + N;
  int*   cursor  = offsets + N;
  int*   srclist = cursor + N;

  hipMemsetAsync(counts, 0, (size_t)N * sizeof(int), stream);
  k_hist<<<1024, 256, 0, stream>>>(dst, counts, E);
  k_scan<<<1, 1024, 0, stream>>>(counts, offsets, N);
  hipMemcpyAsync(cursor, offsets, (size_t)N * sizeof(int),
                 hipMemcpyDeviceToDevice, stream);
  k_scatter<<<1024, 256, 0, stream>>>(src, dst, cursor, srclist, E);

  k_reduce<<<(N + 3) / 4, 256, 0, stream>>>(
      (const float2*)feat, offsets, counts, srclist, (float2*)h, N);

  gcn_gemm<<<1024, 256, 0, stream>>>(h, W, b, out, N);
}

// Round 3
// 435.131 us; speedup vs baseline: 3.4188x; 1.3345x over previous
//
#include <hip/hip_runtime.h>

#define F 128  // feature dim, fixed by the problem

typedef __attribute__((ext_vector_type(8))) short short8;   // 8 bf16 in 4 VGPRs
typedef __attribute__((ext_vector_type(4))) float f32x4;    // MFMA C/D frag

// fp32 -> bf16 round-to-nearest-even (bit trick; NaN irrelevant here)
__device__ inline short f2bf(float f) {
  unsigned u = __float_as_uint(f);
  u += 0x7fff + ((u >> 16) & 1);
  return (short)(u >> 16);
}

// ---------------------------------------------------------------------------
// Pack W into MFMA B-fragments (bf16), one-time 32KB buffer.
// B[k][j] = W[j][k].  Frag id fid = jt*256 + c*64 + lane; element e:
//   B[c*32 + (lane>>4)*8 + e][jt*16 + (lane&15)] = W[jt*16+(lane&15)][c*32+(lane>>4)*8+e]
// ---------------------------------------------------------------------------
__global__ __launch_bounds__(256) void k_packW(
    const float* __restrict__ W, short* __restrict__ Wp) {
  for (int fid = threadIdx.x; fid < 2048; fid += 256) {
    const int lane = fid & 63;
    const int c    = (fid >> 6) & 3;
    const int jt   = fid >> 8;
    const int j    = jt * 16 + (lane & 15);
    const int k0   = c * 32 + (lane >> 4) * 8;
    short8 s;
    #pragma unroll
    for (int i = 0; i < 8; ++i) s[i] = f2bf(W[j * F + k0 + i]);
    *reinterpret_cast<short8*>(Wp + fid * 8) = s;
  }
}

// ---------------------------------------------------------------------------
// Y = X @ W^T  via mfma_f32_16x16x32_bf16.  LDS-free: A frags loaded from
// global fp32 + converted in-register; B frags from the packed 32KB buffer
// (L1/L2-resident, reused by every wave).  One wave per 16-row tile.
// A layout: lane l elem e -> A[row0 + (l&15)][c*32 + (l>>4)*8 + e]
// D layout: lane l reg r  -> D[row0 + (l>>4)*4 + r][jt*16 + (l&15)]
// ---------------------------------------------------------------------------
__global__ __launch_bounds__(256) void k_gemm(
    const float* __restrict__ X, const short* __restrict__ Wp,
    float* __restrict__ Y, int N, int nTiles) {
  const int lane = threadIdx.x & 63;
  const int tile = blockIdx.x * 4 + (threadIdx.x >> 6);
  if (tile >= nTiles) return;
  const int row0 = tile * 16;
  const int r    = row0 + (lane & 15);
  const int k0   = (lane >> 4) * 8;

  short8 a[4];
  #pragma unroll
  for (int c = 0; c < 4; ++c) {
    if (r < N) {
      const float* p = X + (size_t)r * F + c * 32 + k0;
      const float4 x0 = *reinterpret_cast<const float4*>(p);
      const float4 x1 = *reinterpret_cast<const float4*>(p + 4);
      a[c][0] = f2bf(x0.x); a[c][1] = f2bf(x0.y);
      a[c][2] = f2bf(x0.z); a[c][3] = f2bf(x0.w);
      a[c][4] = f2bf(x1.x); a[c][5] = f2bf(x1.y);
      a[c][6] = f2bf(x1.z); a[c][7] = f2bf(x1.w);
    } else {
      #pragma unroll
      for (int i = 0; i < 8; ++i) a[c][i] = 0;
    }
  }

  #pragma unroll
  for (int jt = 0; jt < 8; ++jt) {
    f32x4 acc = {0.f, 0.f, 0.f, 0.f};
    #pragma unroll
    for (int c = 0; c < 4; ++c) {
      const short8 bfrag = *reinterpret_cast<const short8*>(
          Wp + ((jt * 4 + c) * 64 + lane) * 8);
      acc = __builtin_amdgcn_mfma_f32_16x16x32_bf16(a[c], bfrag, acc, 0, 0, 0);
    }
    const int col   = jt * 16 + (lane & 15);
    const int rbase = row0 + (lane >> 4) * 4;
    #pragma unroll
    for (int reg = 0; reg < 4; ++reg)
      if (rbase + reg < N) Y[(size_t)(rbase + reg) * F + col] = acc[reg];
  }
}

// ---------------------------------------------------------------------------
// CSR build: histogram -> scan (writes offsets AND cursor) -> bin src by dst.
// ---------------------------------------------------------------------------
__global__ __launch_bounds__(256) void k_hist(
    const int* __restrict__ dst, int* __restrict__ counts, int E) {
  const int stride = gridDim.x * blockDim.x;
  for (int e = blockIdx.x * blockDim.x + threadIdx.x; e < E; e += stride)
    atomicAdd(&counts[dst[e]], 1);
}

__global__ __launch_bounds__(1024) void k_scan(
    const int* __restrict__ counts, int* __restrict__ offsets,
    int* __restrict__ cursor, int N) {
  __shared__ int part[1024];
  const int t = threadIdx.x;
  const int chunk = (N + 1023) >> 10;
  const int lo = t * chunk;
  const int hi = min(lo + chunk, N);
  int s = 0;
  for (int i = lo; i < hi; ++i) s += counts[i];
  part[t] = s;
  __syncthreads();
  for (int d = 1; d < 1024; d <<= 1) {
    const int add = (t >= d) ? part[t - d] : 0;
    __syncthreads();
    part[t] += add;
    __syncthreads();
  }
  int run = (t > 0) ? part[t - 1] : 0;
  for (int i = lo; i < hi; ++i) {
    offsets[i] = run; cursor[i] = run; run += counts[i];
  }
}

__global__ __launch_bounds__(256) void k_scatter(
    const int* __restrict__ src, const int* __restrict__ dst,
    int* __restrict__ cursor, int* __restrict__ srclist, int E) {
  const int stride = gridDim.x * blockDim.x;
  for (int e = blockIdx.x * blockDim.x + threadIdx.x; e < E; e += stride) {
    const int p = atomicAdd(&cursor[dst[e]], 1);
    srclist[p] = src[e];
  }
}

// ---------------------------------------------------------------------------
// Gather-reduce straight into out: out[v] = b + sum_{e:dst=v} Y[src[e]].
// One wave per node; half-wave per row (float4/lane = 512B/half-wave),
// halves interleave over edges, 2x unrolled; __shfl_xor(32) combine.
// ---------------------------------------------------------------------------
__global__ __launch_bounds__(256) void k_reduce(
    const float4* __restrict__ Y4,      // [N][32]
    const int* __restrict__ offsets,
    const int* __restrict__ counts,
    const int* __restrict__ srclist,
    const float4* __restrict__ b4,      // [32]
    float4* __restrict__ out4,          // [N][32]
    int N) {
  const int lane = threadIdx.x & 63;
  const int half = lane >> 5;
  const int q    = lane & 31;
  const int v    = blockIdx.x * 4 + (threadIdx.x >> 6);
  if (v >= N) return;
  const int off = offsets[v];
  const int deg = counts[v];
  float ax = 0.f, ay = 0.f, az = 0.f, aw = 0.f;
  int k = half;
  for (; k + 2 < deg; k += 4) {            // this half handles k, k+2
    const int s0 = srclist[off + k];
    const int s1 = srclist[off + k + 2];
    const float4 y0 = Y4[(size_t)s0 * 32 + q];
    const float4 y1 = Y4[(size_t)s1 * 32 + q];
    ax += y0.x + y1.x; ay += y0.y + y1.y;
    az += y0.z + y1.z; aw += y0.w + y1.w;
  }
  for (; k < deg; k += 2) {
    const int s = srclist[off + k];
    const float4 y = Y4[(size_t)s * 32 + q];
    ax += y.x; ay += y.y; az += y.z; aw += y.w;
  }
  ax += __shfl_xor(ax, 32); ay += __shfl_xor(ay, 32);
  az += __shfl_xor(az, 32); aw += __shfl_xor(aw, 32);
  if (half == 0) {
    const float4 bb = b4[q];
    out4[(size_t)v * 32 + q] =
        make_float4(ax + bb.x, ay + bb.y, az + bb.z, aw + bb.w);
  }
}

extern "C" void kernel_launch(void* const* d_in, const int* in_sizes, int n_in,
                              void* d_out, int out_size, void* d_ws, size_t ws_size,
                              hipStream_t stream) {
  const float* feat = (const float*)d_in[0];
  const int*   src  = (const int*)d_in[1];
  const int*   dst  = (const int*)d_in[2];
  const float* W    = (const float*)d_in[3];
  const float* b    = (const float*)d_in[4];
  float*       out  = (float*)d_out;

  const int N = in_sizes[0] / F;   // 50000
  const int E = in_sizes[1];       // 1600000

  // Workspace: Y[N*F] f32 | counts[N] | offsets[N] | cursor[N] | srclist[E]
  //            | Wp[16384] bf16   (~32.4 MB total)
  float* Y       = (float*)d_ws;
  int*   counts  = (int*)(Y + (size_t)N * F);
  int*   offsets = counts + N;
  int*   cursor  = offsets + N;
  int*   srclist = cursor + N;
  short* Wp      = (short*)(srclist + E);

  hipMemsetAsync(counts, 0, (size_t)N * sizeof(int), stream);

  k_packW<<<1, 256, 0, stream>>>(W, Wp);

  const int nTiles = (N + 15) / 16;                  // 3125
  k_gemm<<<(nTiles + 3) / 4, 256, 0, stream>>>(feat, Wp, Y, N, nTiles);

  k_hist<<<2048, 256, 0, stream>>>(dst, counts, E);
  k_scan<<<1, 1024, 0, stream>>>(counts, offsets, cursor, N);
  k_scatter<<<2048, 256, 0, stream>>>(src, dst, cursor, srclist, E);

  k_reduce<<<(N + 3) / 4, 256, 0, stream>>>(
      (const float4*)Y, offsets, counts, srclist,
      (const float4*)b, (float4*)out, N);
}

// Round 4
// 116.381 us; speedup vs baseline: 12.7825x; 3.7388x over previous
//
#include <hip/hip_runtime.h>

#define F      128
#define RSH    5            // 32 nodes per bucket
#define RNODES 32
#define NBUCK  1563         // ceil(50000/32) — N fixed at 50000
#define CB     1280         // bucket capacity (mean 1024, +8 sigma)
#define CH     8192         // edges per partition chunk
#define OVCAP  65536

typedef __attribute__((ext_vector_type(8))) short short8;   // 8 bf16
typedef __attribute__((ext_vector_type(4))) float f32x4;    // MFMA C/D frag

__device__ inline short f2bf(float f) {        // fp32 -> bf16 RNE
  unsigned u = __float_as_uint(f);
  u += 0x7fff + ((u >> 16) & 1);
  return (short)(u >> 16);
}
__device__ inline float bf2f(unsigned short u) {
  return __uint_as_float((unsigned)u << 16);
}

// ---------------------------------------------------------------------------
// Init: bucket cursors start at their region base; overflow count = 0.
// ---------------------------------------------------------------------------
__global__ __launch_bounds__(256) void k_init(unsigned* gcur, unsigned* ovcnt) {
  const int i = blockIdx.x * blockDim.x + threadIdx.x;
  if (i < NBUCK) gcur[i] = (unsigned)i * CB;
  else if (i == NBUCK) *ovcnt = 0;
}

// ---------------------------------------------------------------------------
// Pack W into MFMA B-fragments (bf16), one-time 32KB buffer (L1/L2-resident).
// ---------------------------------------------------------------------------
__global__ __launch_bounds__(256) void k_packW(
    const float* __restrict__ W, short* __restrict__ Wp) {
  for (int fid = threadIdx.x; fid < 2048; fid += 256) {
    const int lane = fid & 63;
    const int c    = (fid >> 6) & 3;
    const int jt   = fid >> 8;
    const int j    = jt * 16 + (lane & 15);
    const int k0   = c * 32 + (lane >> 4) * 8;
    short8 s;
    #pragma unroll
    for (int i = 0; i < 8; ++i) s[i] = f2bf(W[j * F + k0 + i]);
    *reinterpret_cast<short8*>(Wp + fid * 8) = s;
  }
}

// ---------------------------------------------------------------------------
// Y = X @ W^T via mfma_f32_16x16x32_bf16 (proven R3 layout), output bf16.
// ---------------------------------------------------------------------------
__global__ __launch_bounds__(256) void k_gemm(
    const float* __restrict__ X, const short* __restrict__ Wp,
    unsigned short* __restrict__ Yb, int N, int nTiles) {
  const int lane = threadIdx.x & 63;
  const int tile = blockIdx.x * 4 + (threadIdx.x >> 6);
  if (tile >= nTiles) return;
  const int row0 = tile * 16;
  const int r    = row0 + (lane & 15);
  const int k0   = (lane >> 4) * 8;

  short8 a[4];
  #pragma unroll
  for (int c = 0; c < 4; ++c) {
    if (r < N) {
      const float* p = X + (size_t)r * F + c * 32 + k0;
      const float4 x0 = *reinterpret_cast<const float4*>(p);
      const float4 x1 = *reinterpret_cast<const float4*>(p + 4);
      a[c][0] = f2bf(x0.x); a[c][1] = f2bf(x0.y);
      a[c][2] = f2bf(x0.z); a[c][3] = f2bf(x0.w);
      a[c][4] = f2bf(x1.x); a[c][5] = f2bf(x1.y);
      a[c][6] = f2bf(x1.z); a[c][7] = f2bf(x1.w);
    } else {
      #pragma unroll
      for (int i = 0; i < 8; ++i) a[c][i] = 0;
    }
  }

  #pragma unroll
  for (int jt = 0; jt < 8; ++jt) {
    f32x4 acc = {0.f, 0.f, 0.f, 0.f};
    #pragma unroll
    for (int c = 0; c < 4; ++c) {
      const short8 bfrag = *reinterpret_cast<const short8*>(
          Wp + ((jt * 4 + c) * 64 + lane) * 8);
      acc = __builtin_amdgcn_mfma_f32_16x16x32_bf16(a[c], bfrag, acc, 0, 0, 0);
    }
    const int col   = jt * 16 + (lane & 15);
    const int rbase = row0 + (lane >> 4) * 4;
    #pragma unroll
    for (int reg = 0; reg < 4; ++reg)
      if (rbase + reg < N)
        Yb[(size_t)(rbase + reg) * F + col] = (unsigned short)f2bf(acc[reg]);
  }
}

// ---------------------------------------------------------------------------
// Multisplit partition: chunk -> LDS hist over NBUCK buckets -> LDS scan ->
// LDS reorder -> contiguous flush per bucket via global cursor bump.
// Entry = src(16b) | dst_local(5b)<<16 | bucket(11b)<<21.
// ---------------------------------------------------------------------------
__global__ __launch_bounds__(512) void k_partition(
    const int* __restrict__ src, const int* __restrict__ dst,
    unsigned* __restrict__ pk,            // [NBUCK*CB]
    unsigned* __restrict__ gcur,          // [NBUCK], init b*CB
    unsigned* __restrict__ ovcnt,
    unsigned long long* __restrict__ ovlist,
    int E) {
  __shared__ unsigned lpk[CH];            // 32 KB
  __shared__ unsigned cnt[NBUCK];         // 6.25 KB
  __shared__ unsigned offs[NBUCK];        // 6.25 KB
  __shared__ unsigned cur[NBUCK];         // 6.25 KB (also scan scratch[512])
  __shared__ unsigned gbase[NBUCK];       // 6.25 KB   -> total ~57 KB
  const int t = threadIdx.x;
  const int nchunk = (E + CH - 1) / CH;

  for (int c = blockIdx.x; c < nchunk; c += gridDim.x) {
    const int e0   = c * CH;
    const int ecnt = min(CH, E - e0);

    for (int i = t; i < NBUCK; i += 512) cnt[i] = 0;
    __syncthreads();

    // 1. histogram
    for (int i = t; i < ecnt; i += 512)
      atomicAdd(&cnt[(unsigned)dst[e0 + i] >> RSH], 1u);
    __syncthreads();

    // 2. exclusive scan over NBUCK (4 per thread + 512-wide Hillis-Steele)
    unsigned lv0, lv1, lv2, lv3;
    {
      const int i0 = t * 4;
      lv0 = (i0 + 0 < NBUCK) ? cnt[i0 + 0] : 0;
      lv1 = (i0 + 1 < NBUCK) ? cnt[i0 + 1] : 0;
      lv2 = (i0 + 2 < NBUCK) ? cnt[i0 + 2] : 0;
      lv3 = (i0 + 3 < NBUCK) ? cnt[i0 + 3] : 0;
    }
    cur[t] = lv0 + lv1 + lv2 + lv3;       // scratch use of cur[0..511]
    __syncthreads();
    for (int d2 = 1; d2 < 512; d2 <<= 1) {
      const unsigned add = (t >= d2) ? cur[t - d2] : 0;
      __syncthreads();
      cur[t] += add;
      __syncthreads();
    }
    unsigned ebase = (t > 0) ? cur[t - 1] : 0;
    __syncthreads();                       // done reading scratch
    {
      const int i0 = t * 4;
      if (i0 + 0 < NBUCK) { offs[i0 + 0] = ebase; cur[i0 + 0] = ebase; ebase += lv0; }
      if (i0 + 1 < NBUCK) { offs[i0 + 1] = ebase; cur[i0 + 1] = ebase; ebase += lv1; }
      if (i0 + 2 < NBUCK) { offs[i0 + 2] = ebase; cur[i0 + 2] = ebase; ebase += lv2; }
      if (i0 + 3 < NBUCK) { offs[i0 + 3] = ebase; cur[i0 + 3] = ebase; ebase += lv3; }
    }
    __syncthreads();

    // 3. reorder into LDS, carrying bucket id in bits [21..31]
    for (int i = t; i < ecnt; i += 512) {
      const unsigned d = (unsigned)dst[e0 + i];
      const unsigned b = d >> RSH;
      const unsigned p = atomicAdd(&cur[b], 1u);
      lpk[p] = (unsigned)src[e0 + i] | ((d & (RNODES - 1)) << 16) | (b << 21);
    }
    __syncthreads();

    // 4. reserve global space per bucket
    for (int i = t; i < NBUCK; i += 512)
      if (cnt[i] > 0) gbase[i] = atomicAdd(&gcur[i], cnt[i]);
    __syncthreads();

    // 5. contiguous flush (runs of same bucket -> coalesced)
    for (int p = t; p < ecnt; p += 512) {
      const unsigned v = lpk[p];
      const unsigned b = v >> 21;
      const unsigned idx = gbase[b] + ((unsigned)p - offs[b]);
      if (idx < (b + 1) * (unsigned)CB) {
        pk[idx] = v & 0x1FFFFFu;           // strip bucket bits
      } else {                              // overflow (expected: never)
        const unsigned o = atomicAdd(ovcnt, 1u);
        if (o < OVCAP) {
          const unsigned s  = v & 0xFFFFu;
          const unsigned dl = (v >> 16) & (RNODES - 1);
          ovlist[o] = ((unsigned long long)(b * RNODES + dl) << 32) | s;
        }
      }
    }
    __syncthreads();
  }
}

// ---------------------------------------------------------------------------
// Per-bucket CSR: group the bucket's entries by node (in place in the padded
// region, u16 src ids), emit absolute offsets/counts per node.
// ---------------------------------------------------------------------------
__global__ __launch_bounds__(256) void k_csr(
    const unsigned* __restrict__ pk,
    const unsigned* __restrict__ gcur,
    unsigned short* __restrict__ csr,     // [NBUCK*CB]
    int* __restrict__ offsets,            // [N]
    int* __restrict__ counts,             // [N]
    int N) {
  __shared__ unsigned lcnt[RNODES], loffs[RNODES], lcur[RNODES];
  const int b = blockIdx.x;
  const unsigned base = (unsigned)b * CB;
  const unsigned m = min(gcur[b] - base, (unsigned)CB);
  const int t = threadIdx.x;
  if (t < RNODES) lcnt[t] = 0;
  __syncthreads();
  for (unsigned i = t; i < m; i += 256)
    atomicAdd(&lcnt[pk[base + i] >> 16], 1u);
  __syncthreads();
  if (t == 0) {
    unsigned r = 0;
    #pragma unroll
    for (int i = 0; i < RNODES; ++i) { loffs[i] = r; lcur[i] = r; r += lcnt[i]; }
  }
  __syncthreads();
  for (unsigned i = t; i < m; i += 256) {
    const unsigned v  = pk[base + i];
    const unsigned p  = atomicAdd(&lcur[v >> 16], 1u);  // absolute in bucket
    csr[base + p] = (unsigned short)(v & 0xFFFFu);
  }
  __syncthreads();
  if (t < RNODES) {
    const int v = b * RNODES + t;
    if (v < N) {
      offsets[v] = (int)(base + loffs[t]);
      counts[v]  = (int)lcnt[t];
    }
  }
}

// ---------------------------------------------------------------------------
// Gather-reduce into out: out[v] = b + sum Y[src].  One wave per node;
// half-wave per bf16 row (ushort4/lane = 256B), halves interleave edges.
// ---------------------------------------------------------------------------
__global__ __launch_bounds__(256) void k_reduce(
    const unsigned short* __restrict__ Yb,   // [N][128] bf16
    const int* __restrict__ offsets,
    const int* __restrict__ counts,
    const unsigned short* __restrict__ csr,
    const float4* __restrict__ b4,           // [32]
    float4* __restrict__ out4,               // [N][32]
    int N) {
  const int lane = threadIdx.x & 63;
  const int half = lane >> 5;
  const int q    = lane & 31;
  const int v    = blockIdx.x * 4 + (threadIdx.x >> 6);
  if (v >= N) return;
  const int off = offsets[v];
  const int deg = counts[v];
  float a0 = 0.f, a1 = 0.f, a2 = 0.f, a3 = 0.f;
  int k = half;
  for (; k + 2 < deg; k += 4) {
    const int s0 = csr[off + k];
    const int s1 = csr[off + k + 2];
    const ushort4 y0 = *reinterpret_cast<const ushort4*>(Yb + (size_t)s0 * F + q * 4);
    const ushort4 y1 = *reinterpret_cast<const ushort4*>(Yb + (size_t)s1 * F + q * 4);
    a0 += bf2f(y0.x) + bf2f(y1.x);
    a1 += bf2f(y0.y) + bf2f(y1.y);
    a2 += bf2f(y0.z) + bf2f(y1.z);
    a3 += bf2f(y0.w) + bf2f(y1.w);
  }
  for (; k < deg; k += 2) {
    const int s = csr[off + k];
    const ushort4 y = *reinterpret_cast<const ushort4*>(Yb + (size_t)s * F + q * 4);
    a0 += bf2f(y.x); a1 += bf2f(y.y); a2 += bf2f(y.z); a3 += bf2f(y.w);
  }
  a0 += __shfl_xor(a0, 32); a1 += __shfl_xor(a1, 32);
  a2 += __shfl_xor(a2, 32); a3 += __shfl_xor(a3, 32);
  if (half == 0) {
    const float4 bb = b4[q];
    out4[(size_t)v * 32 + q] =
        make_float4(a0 + bb.x, a1 + bb.y, a2 + bb.z, a3 + bb.w);
  }
}

// ---------------------------------------------------------------------------
// Overflow fallback (expected empty): wave per edge, fp32 atomics into out.
// ---------------------------------------------------------------------------
__global__ __launch_bounds__(256) void k_overflow(
    const unsigned* __restrict__ ovcnt,
    const unsigned long long* __restrict__ ovlist,
    const unsigned short* __restrict__ Yb,
    float* __restrict__ out) {
  const unsigned n = min(*ovcnt, (unsigned)OVCAP);
  const int lane = threadIdx.x & 63;
  const int w  = (int)((blockIdx.x * blockDim.x + threadIdx.x) >> 6);
  const int nw = (int)((gridDim.x * blockDim.x) >> 6);
  for (unsigned i = w; i < n; i += nw) {
    const unsigned long long e = ovlist[i];
    const unsigned s = (unsigned)(e & 0xFFFFFFFFu);
    const unsigned d = (unsigned)(e >> 32);
    const float x0 = bf2f(Yb[(size_t)s * F + lane * 2]);
    const float x1 = bf2f(Yb[(size_t)s * F + lane * 2 + 1]);
    unsafeAtomicAdd(&out[(size_t)d * F + lane * 2],     x0);
    unsafeAtomicAdd(&out[(size_t)d * F + lane * 2 + 1], x1);
  }
}

extern "C" void kernel_launch(void* const* d_in, const int* in_sizes, int n_in,
                              void* d_out, int out_size, void* d_ws, size_t ws_size,
                              hipStream_t stream) {
  const float* feat = (const float*)d_in[0];
  const int*   src  = (const int*)d_in[1];
  const int*   dst  = (const int*)d_in[2];
  const float* W    = (const float*)d_in[3];
  const float* b    = (const float*)d_in[4];
  float*       out  = (float*)d_out;

  const int N = in_sizes[0] / F;   // 50000
  const int E = in_sizes[1];       // 1600000

  // Workspace layout (~26 MB), 256B-aligned sections.
  char* w = (char*)d_ws;
  auto alloc = [&](size_t bytes) {
    char* p = w; w += (bytes + 255) & ~(size_t)255; return p;
  };
  unsigned short*     Yb      = (unsigned short*)alloc((size_t)N * F * 2);
  short*              Wp      = (short*)alloc(2048 * 8 * 2);
  unsigned*           pk      = (unsigned*)alloc((size_t)NBUCK * CB * 4);
  unsigned short*     csr     = (unsigned short*)alloc((size_t)NBUCK * CB * 2);
  int*                offsets = (int*)alloc((size_t)N * 4);
  int*                counts  = (int*)alloc((size_t)N * 4);
  unsigned*           gcur    = (unsigned*)alloc((size_t)NBUCK * 4);
  unsigned*           ovcnt   = (unsigned*)alloc(4);
  unsigned long long* ovlist  = (unsigned long long*)alloc((size_t)OVCAP * 8);

  k_init<<<(NBUCK + 256) / 256, 256, 0, stream>>>(gcur, ovcnt);
  k_packW<<<1, 256, 0, stream>>>(W, Wp);

  const int nTiles = (N + 15) / 16;                       // 3125
  k_gemm<<<(nTiles + 3) / 4, 256, 0, stream>>>(feat, Wp, Yb, N, nTiles);

  const int nchunk = (E + CH - 1) / CH;                   // 196
  k_partition<<<nchunk, 512, 0, stream>>>(src, dst, pk, gcur, ovcnt, ovlist, E);
  k_csr<<<NBUCK, 256, 0, stream>>>(pk, gcur, csr, offsets, counts, N);

  k_reduce<<<(N + 3) / 4, 256, 0, stream>>>(
      Yb, offsets, counts, csr, (const float4*)b, (float4*)out, N);
  k_overflow<<<16, 256, 0, stream>>>(ovcnt, ovlist, Yb, out);
}